// Round 7
// baseline (231.621 us; speedup 1.0000x reference)
//
#include <hip/hip_runtime.h>

#define BB 32
#define TT 36
#define NN 10000
#define FF 3
#define HH 10
#define RR 20
#define NQ (NN / 4)   // 2500 node-quads per batch

typedef float v4f __attribute__((ext_vector_type(4)));

// ws layout (floats):
//   [0]             : nan-list counter (as int)
//   [1]             : g1
//   [2, +BB*RR)     : per-(b,region) sum of node means
//   [.., +BB*RR)    : per-(b,region) count of valid nodes
//   [.., +BB*NN)    : nan-list entries (int, capacity BB*NN — cannot overflow)

// Fused stage 1: nanmean over T per node (nt streaming reads), writes the
// 10 horizon rows directly (nt stores), accumulates region sums.
// All-NaN nodes write NaN and get recorded for post-g1 fixup.
__global__ __launch_bounds__(256) void k_time_mean(
        const float* __restrict__ seq,
        const int* __restrict__ cid,
        float* __restrict__ out,
        float* __restrict__ rsum,
        float* __restrict__ rcnt,
        int* __restrict__ nancnt,
        int* __restrict__ nanlist) {
    __shared__ float ls[RR];
    __shared__ float lc[RR];
    const int b = blockIdx.y;
    const int q = blockIdx.x * blockDim.x + threadIdx.x;  // quad index 0..2499
    if (threadIdx.x < RR) { ls[threadIdx.x] = 0.f; lc[threadIdx.x] = 0.f; }
    __syncthreads();

    if (q < NQ) {
        const v4f* p = (const v4f*)seq + (size_t)b * TT * NN * FF / 4 + 3 * q;
        const size_t tstride = (size_t)NN * FF / 4;  // 7500 float4s per t
        float s0 = 0.f, s1 = 0.f, s2 = 0.f, s3 = 0.f;
        int c0 = 0, c1 = 0, c2 = 0, c3 = 0;
        #pragma unroll
        for (int t = 0; t < TT; ++t) {
            v4f a0 = __builtin_nontemporal_load(p);
            v4f a1 = __builtin_nontemporal_load(p + 1);
            v4f a2 = __builtin_nontemporal_load(p + 2);
            p += tstride;
            float v0 = a0.x, v1 = a0.w, v2 = a1.z, v3 = a2.y;
            if (v0 == v0) { s0 += v0; c0++; }
            if (v1 == v1) { s1 += v1; c1++; }
            if (v2 == v2) { s2 += v2; c2++; }
            if (v3 == v3) { s3 += v3; c3++; }
        }
        const float nanf_ = __int_as_float(0x7fc00000);
        float m0 = c0 ? s0 / (float)c0 : nanf_;
        float m1 = c1 ? s1 / (float)c1 : nanf_;
        float m2 = c2 ? s2 / (float)c2 : nanf_;
        float m3 = c3 ? s3 / (float)c3 : nanf_;

        // fused pred write: 10 horizon rows, coalesced float4 stores
        v4f mv; mv.x = m0; mv.y = m1; mv.z = m2; mv.w = m3;
        v4f* o = (v4f*)out + (size_t)b * HH * NQ + q;
        #pragma unroll
        for (int h = 0; h < HH; ++h)
            __builtin_nontemporal_store(mv, o + (size_t)h * NQ);

        // record all-NaN nodes for post-g1 fixup (effectively never taken)
        if (!c0) { int i = atomicAdd(nancnt, 1); nanlist[i] = b * NN + 4 * q; }
        if (!c1) { int i = atomicAdd(nancnt, 1); nanlist[i] = b * NN + 4 * q + 1; }
        if (!c2) { int i = atomicAdd(nancnt, 1); nanlist[i] = b * NN + 4 * q + 2; }
        if (!c3) { int i = atomicAdd(nancnt, 1); nanlist[i] = b * NN + 4 * q + 3; }

        const int4 r4 = ((const int4*)cid)[q];
        if (c0) { atomicAdd(&ls[r4.x], m0); atomicAdd(&lc[r4.x], 1.f); }
        if (c1) { atomicAdd(&ls[r4.y], m1); atomicAdd(&lc[r4.y], 1.f); }
        if (c2) { atomicAdd(&ls[r4.z], m2); atomicAdd(&lc[r4.z], 1.f); }
        if (c3) { atomicAdd(&ls[r4.w], m3); atomicAdd(&lc[r4.w], 1.f); }
    }

    __syncthreads();
    if (threadIdx.x < RR) {
        atomicAdd(&rsum[b * RR + threadIdx.x], ls[threadIdx.x]);
        atomicAdd(&rcnt[b * RR + threadIdx.x], lc[threadIdx.x]);
    }
}

// single block, 640 threads. Computes regional means, g2 backfill, and
// g1 = sum(rsum)/sum(rcnt) (== global nanmean over node means).
__global__ void k_regional(const float* __restrict__ rsum,
                           const float* __restrict__ rcnt,
                           float* __restrict__ g1out,
                           float* __restrict__ out_reg) {
    const int tid = threadIdx.x;
    __shared__ float sv[10], sc[10], ss[10], sn[10];
    __shared__ float g2s;

    float myrs = 0.f, myrc = 0.f;
    float val = 0.f;
    int valid = 0;
    if (tid < BB * RR) {
        myrs = rsum[tid];
        myrc = rcnt[tid];
        if (myrc > 0.f) { val = myrs / myrc; valid = 1; }
    }

    float wv = valid ? val : 0.f;
    float wc = (float)valid;
    float ws = myrs;
    float wn = myrc;
    for (int off = 32; off > 0; off >>= 1) {
        wv += __shfl_down(wv, off, 64);
        wc += __shfl_down(wc, off, 64);
        ws += __shfl_down(ws, off, 64);
        wn += __shfl_down(wn, off, 64);
    }
    const int wave = tid >> 6;
    if ((tid & 63) == 0) { sv[wave] = wv; sc[wave] = wc; ss[wave] = ws; sn[wave] = wn; }
    __syncthreads();

    if (tid == 0) {
        float v = 0.f, c = 0.f, s = 0.f, n = 0.f;
        #pragma unroll
        for (int i = 0; i < 10; ++i) { v += sv[i]; c += sc[i]; s += ss[i]; n += sn[i]; }
        g2s = v / c;
        g1out[0] = s / n;
    }
    __syncthreads();

    if (tid < BB * RR) {
        const int b = tid / RR, r = tid % RR;
        const float o = valid ? val : g2s;
        #pragma unroll
        for (int h = 0; h < HH; ++h)
            out_reg[(size_t)(b * HH + h) * RR + r] = o;
    }
}

// Replace out_pred entries of all-NaN nodes with g1 (runs after k_regional;
// normally zero entries -> instant).
__global__ void k_fix(const int* __restrict__ nancnt,
                      const int* __restrict__ nanlist,
                      const float* __restrict__ g1p,
                      float* __restrict__ out) {
    const int cnt = nancnt[0];
    const float g1 = g1p[0];
    for (int i = blockIdx.x * blockDim.x + threadIdx.x; i < cnt;
         i += gridDim.x * blockDim.x) {
        const int bn = nanlist[i];
        const int b = bn / NN, n = bn % NN;
        float* o = out + (size_t)b * HH * NN + n;
        #pragma unroll
        for (int h = 0; h < HH; ++h)
            o[(size_t)h * NN] = g1;
    }
}

extern "C" void kernel_launch(void* const* d_in, const int* in_sizes, int n_in,
                              void* d_out, int out_size, void* d_ws, size_t ws_size,
                              hipStream_t stream) {
    const float* seq = (const float*)d_in[0];
    const int*   cid = (const int*)d_in[1];
    float* out = (float*)d_out;

    float* ws      = (float*)d_ws;
    int*   nancnt  = (int*)ws;                 // 1
    float* g1      = ws + 1;                   // 1
    float* rsum    = ws + 2;                   // BB*RR
    float* rcnt    = rsum + BB * RR;           // BB*RR
    int*   nanlist = (int*)(rcnt + BB * RR);   // BB*NN capacity

    // zero counter + accumulators (ws is poisoned 0xAA before every launch)
    hipMemsetAsync(nancnt, 0, (size_t)(2 + 2 * BB * RR) * sizeof(float), stream);

    dim3 blk(256);
    dim3 grd((NQ + 255) / 256, BB);       // 10 x 32 = 320 blocks
    k_time_mean<<<grd, blk, 0, stream>>>(seq, cid, out, rsum, rcnt,
                                         nancnt, nanlist);
    k_regional<<<1, 640, 0, stream>>>(rsum, rcnt, g1,
                                      out + (size_t)BB * HH * NN);
    k_fix<<<40, 256, 0, stream>>>(nancnt, nanlist, g1, out);
}

// Round 8
// 207.562 us; speedup vs baseline: 1.1159x; 1.1159x over previous
//
#include <hip/hip_runtime.h>

#define BB 32
#define TT 36
#define NN 10000
#define FF 3
#define HH 10
#define RR 20
#define NQ (NN / 4)        // 2500 node-quads per batch
#define NC (NN * FF / 4)   // 7500 float4 columns per (b,t) row

// ws layout (floats):
//   [0, BB*NN)      : time_mean (NaN where node all-NaN)
//   [+BB*RR]        : per-(b,region) sum of node means
//   [+BB*RR]        : per-(b,region) count of valid nodes
//   [+1]            : g1

// Stage 1, column-owner form: thread owns ONE float4 column c across all T.
// ch0 words (multiples of 3) within column c: c=3k -> {.x=node 4k, .w=node 4k+1},
// c=3k+1 -> {.z=node 4k+2}, c=3k+2 -> {.y=node 4k+3}.
// One 16B load + ~6 VALU per iteration, no LDS staging, no barriers in loop.
__global__ __launch_bounds__(256) void k_time_mean(
        const float4* __restrict__ seq4,
        const int* __restrict__ cid,
        float* __restrict__ tm,
        float* __restrict__ rsum,
        float* __restrict__ rcnt) {
    __shared__ float ls[RR];
    __shared__ float lc[RR];
    const int b = blockIdx.y;
    const int c = blockIdx.x * blockDim.x + threadIdx.x;   // column 0..7499
    if (threadIdx.x < RR) { ls[threadIdx.x] = 0.f; lc[threadIdx.x] = 0.f; }
    __syncthreads();

    if (c < NC) {
        const int k = c / 3;
        const int r = c - 3 * k;            // 0,1,2 — lane class
        const float4* p = seq4 + (size_t)b * TT * NC + c;

        float sA = 0.f, sB = 0.f;
        int   cA = 0,   cB = 0;
        #pragma unroll
        for (int t = 0; t < TT; ++t) {
            const float4 a = p[(size_t)t * NC];
            // predicated component select: no branches, no divergence
            const float vA = (r == 0) ? a.x : ((r == 1) ? a.z : a.y);
            const float vB = a.w;           // meaningful only for r==0
            if (vA == vA)           { sA += vA; cA++; }
            if (r == 0 && vB == vB) { sB += vB; cB++; }
        }

        const float nanf_ = __int_as_float(0x7fc00000);
        const int nA = (r == 0) ? 4 * k : ((r == 1) ? 4 * k + 2 : 4 * k + 3);
        const float mA = cA ? sA / (float)cA : nanf_;
        tm[b * NN + nA] = mA;
        if (cA) {
            const int rg = cid[nA];
            atomicAdd(&ls[rg], mA);
            atomicAdd(&lc[rg], 1.f);
        }
        if (r == 0) {
            const int nB = 4 * k + 1;
            const float mB = cB ? sB / (float)cB : nanf_;
            tm[b * NN + nB] = mB;
            if (cB) {
                const int rg = cid[nB];
                atomicAdd(&ls[rg], mB);
                atomicAdd(&lc[rg], 1.f);
            }
        }
    }

    __syncthreads();
    // spread-address global atomics: 640 accumulators, no single-address herd
    if (threadIdx.x < RR) {
        atomicAdd(&rsum[b * RR + threadIdx.x], ls[threadIdx.x]);
        atomicAdd(&rcnt[b * RR + threadIdx.x], lc[threadIdx.x]);
    }
}

// single block, 640 threads. Regional means + g2 backfill + g1 = Σrsum/Σrcnt.
__global__ void k_regional(const float* __restrict__ rsum,
                           const float* __restrict__ rcnt,
                           float* __restrict__ g1out,
                           float* __restrict__ out_reg) {
    const int tid = threadIdx.x;
    __shared__ float sv[10], sc[10], ss[10], sn[10];
    __shared__ float g2s;

    float myrs = 0.f, myrc = 0.f;
    float val = 0.f;
    int valid = 0;
    if (tid < BB * RR) {
        myrs = rsum[tid];
        myrc = rcnt[tid];
        if (myrc > 0.f) { val = myrs / myrc; valid = 1; }
    }

    float wv = valid ? val : 0.f;
    float wc = (float)valid;
    float ws = myrs;
    float wn = myrc;
    for (int off = 32; off > 0; off >>= 1) {
        wv += __shfl_down(wv, off, 64);
        wc += __shfl_down(wc, off, 64);
        ws += __shfl_down(ws, off, 64);
        wn += __shfl_down(wn, off, 64);
    }
    const int wave = tid >> 6;
    if ((tid & 63) == 0) { sv[wave] = wv; sc[wave] = wc; ss[wave] = ws; sn[wave] = wn; }
    __syncthreads();

    if (tid == 0) {
        float v = 0.f, cc = 0.f, s = 0.f, n = 0.f;
        #pragma unroll
        for (int i = 0; i < 10; ++i) { v += sv[i]; cc += sc[i]; s += ss[i]; n += sn[i]; }
        g2s = v / cc;
        g1out[0] = s / n;
    }
    __syncthreads();

    if (tid < BB * RR) {
        const int b = tid / RR, r = tid % RR;
        const float o = valid ? val : g2s;
        #pragma unroll
        for (int h = 0; h < HH; ++h)
            out_reg[(size_t)(b * HH + h) * RR + r] = o;
    }
}

__global__ __launch_bounds__(256) void k_pred(
        const float* __restrict__ tm,
        const float* __restrict__ g1p,
        float* __restrict__ out) {
    const int b = blockIdx.y;
    const int q = blockIdx.x * blockDim.x + threadIdx.x;  // quad 0..2499
    if (q >= NQ) return;
    const float g1 = g1p[0];
    float4 v = ((const float4*)tm)[(size_t)b * NQ + q];
    if (!(v.x == v.x)) v.x = g1;
    if (!(v.y == v.y)) v.y = g1;
    if (!(v.z == v.z)) v.z = g1;
    if (!(v.w == v.w)) v.w = g1;
    float4* o = (float4*)out + (size_t)b * HH * NQ + q;
    #pragma unroll
    for (int h = 0; h < HH; ++h)
        o[(size_t)h * NQ] = v;
}

extern "C" void kernel_launch(void* const* d_in, const int* in_sizes, int n_in,
                              void* d_out, int out_size, void* d_ws, size_t ws_size,
                              hipStream_t stream) {
    const float* seq = (const float*)d_in[0];
    const int*   cid = (const int*)d_in[1];
    float* out = (float*)d_out;

    float* ws   = (float*)d_ws;
    float* tm   = ws;                     // BB*NN
    float* rsum = tm + BB * NN;           // BB*RR
    float* rcnt = rsum + BB * RR;         // BB*RR
    float* g1   = rcnt + BB * RR;         // 1

    hipMemsetAsync(rsum, 0, (size_t)(2 * BB * RR) * sizeof(float), stream);

    dim3 blk(256);
    dim3 grdA((NC + 255) / 256, BB);      // 30 x 32 = 960 blocks
    dim3 grdP((NQ + 255) / 256, BB);      // 10 x 32 = 320 blocks
    k_time_mean<<<grdA, blk, 0, stream>>>((const float4*)seq, cid, tm, rsum, rcnt);
    k_regional<<<1, 640, 0, stream>>>(rsum, rcnt, g1,
                                      out + (size_t)BB * HH * NN);
    k_pred<<<grdP, blk, 0, stream>>>(tm, g1, out);
}